// Round 9
// baseline (181.683 us; speedup 1.0000x reference)
//
#include <hip/hip_runtime.h>
#include <hip/hip_bf16.h>
#include <stdint.h>

#define NB 32
#define NC 512
#define NP 576
#define NN 4096
#define APANEL8 294912u  // NP*NC bytes (fp8)
#define ATILE8 18432u    // NP*32 bytes per k-tile

typedef __attribute__((ext_vector_type(4))) float floatx4;

#define GLOAD_F32(dst, voff, sbase) \
  asm volatile("global_load_dword %0, %1, %2" : "=v"(dst) : "v"(voff), "s"(sbase))
#define GLOAD_B64(dst, voff, sbase) \
  asm volatile("global_load_dwordx2 %0, %1, %2" : "=v"(dst) : "v"(voff), "s"(sbase))
#define DSWRITE_B64(addr, data) \
  asm volatile("ds_write_b64 %0, %1" :: "v"(addr), "v"(data))
#define WAIT_VMCNT(N) asm volatile("s_waitcnt vmcnt(" #N ")" ::: "memory")
#define WAIT_LGKM0    asm volatile("s_waitcnt lgkmcnt(0)" ::: "memory")
#define SCHEDBAR() __builtin_amdgcn_sched_barrier(0)

// ---------------- K1: inverse L2 norms over channel dim (patch only) ----------------
__global__ void norms_kernel(const float* __restrict__ in, float* __restrict__ invn,
                             int nsp, int total) {
  int idx = blockIdx.x * 256 + threadIdx.x;
  if (idx >= total) return;
  int b = idx / nsp, sp = idx - b * nsp;
  const float* p = in + (size_t)b * NC * nsp + sp;
  float s = 0.f;
#pragma unroll 8
  for (int c = 0; c < NC; ++c) { float v = p[(size_t)c * nsp]; s = fmaf(v, v, s); }
  invn[idx] = 1.0f / fmaxf(sqrtf(s), 1e-12f);
}

// ---------------- K2: patch [C][P] -> fp8 fragment-tiled A2, scale ----------------
__global__ void transpose_kernel(const float* __restrict__ in, const float* __restrict__ invn,
                                 uint8_t* __restrict__ out, int nsp) {
  __shared__ float tile[64][65];
  int b = blockIdx.z, c0 = blockIdx.y * 64, p0 = blockIdx.x * 64;
  int tx = threadIdx.x & 63, ty = threadIdx.x >> 6;
  const float* src = in + ((size_t)b * NC + c0) * nsp + p0;
#pragma unroll
  for (int r = ty; r < 64; r += 4) tile[r][tx] = src[(size_t)r * nsp + tx];
  __syncthreads();
  int p = p0 + tx;
  float iv = invn[b * nsp + p];
  char* dst = (char*)out + (size_t)b * APANEL8
            + (uint32_t)(p >> 4) * 512u + (uint32_t)(p & 15) * 8u;
#pragma unroll
  for (int q = ty; q < 8; q += 4) {
    int c_local = q * 8, c_global = c0 + c_local;
    float f[8];
#pragma unroll
    for (int e = 0; e < 8; ++e) f[e] = tile[c_local + e][tx] * iv;
    int lo = 0, hi = 0;
    lo = __builtin_amdgcn_cvt_pk_fp8_f32(f[0], f[1], lo, false);
    lo = __builtin_amdgcn_cvt_pk_fp8_f32(f[2], f[3], lo, true);
    hi = __builtin_amdgcn_cvt_pk_fp8_f32(f[4], f[5], hi, false);
    hi = __builtin_amdgcn_cvt_pk_fp8_f32(f[6], f[7], hi, true);
    union { int i2[2]; long l; } u; u.i2[0] = lo; u.i2[1] = hi;
    uint32_t kt = (uint32_t)c_global >> 5, gg = ((uint32_t)c_global >> 3) & 3u;
    *(long*)(dst + kt * ATILE8 + gg * 128u) = u.l;
  }
}

// ---------------- K3: fused GEMM + softmax-reduction ----------------
// Block = 2 waves sharing one (b,jc). Phase 1: wave w stages k-half w of the
// 64-j x-slice (coalesced fp32), packs fp8 in-register, writes the block's
// 32 KB LDS B-panel (bank-floor swizzle). ONE barrier. Phase 2: each wave
// independently does 3 chunks x 96 rows (acc[6][4], 96 AGPR), A-frags
// contiguous from A2 with depth-2 ping-pong + vmcnt(6), B-frags from LDS.
__global__ __launch_bounds__(128, 2)
void affinity_kernel(const uint8_t* __restrict__ A2,
                     const float* __restrict__ x,
                     float* __restrict__ partials) {
  const int bid = blockIdx.x;
  const int T = (bid & 7) * 256 + (bid >> 3);   // bijective XCD swizzle (2048 = 8*256)
  const int b = T >> 6, jc = T & 63;
  const int tid = threadIdx.x, lane = tid & 63, w = tid >> 6;
  const int g = lane >> 4, l15 = lane & 15;

  __shared__ __align__(16) char Bsh[32768];
  __shared__ float sqx[2][64];
  __shared__ float invd[64];

  const uint64_t sA = (uint64_t)(uintptr_t)A2;
  const uint64_t sX = (uint64_t)(uintptr_t)x;
  const uint32_t ldsB = (uint32_t)(uintptr_t)(&Bsh[0]);

  // ---- phase 1: stage own k-half (8 batches x 32 rows), pack -> LDS ----
  const uint32_t vGbase = (uint32_t)(b * NC + w * 256) * (uint32_t)(NN * 4)
                        + (uint32_t)(jc * 64 + lane) * 4u;
  float GR[32], GS[32];
  float sq = 0.f;

  auto issueBatch = [&](int bt, float (&G)[32]) {
#pragma unroll
    for (int r = 0; r < 32; ++r)
      GLOAD_F32(G[r], vGbase + (uint32_t)(bt * 32 + r) * (uint32_t)(NN * 4), sX);
  };
  // LDS write: granule (kt, gg, j=lane) at kt*2048 + gg*512 + (j>>4)*128 + ((j+gg)&15)*8
  auto packWrite = [&](float (&G)[32], int bt) {
    int kt = w * 8 + bt;
#pragma unroll
    for (int gg = 0; gg < 4; ++gg) {
#pragma unroll
      for (int e = 0; e < 8; ++e) sq = fmaf(G[gg * 8 + e], G[gg * 8 + e], sq);
      int lo = 0, hi = 0;
      lo = __builtin_amdgcn_cvt_pk_fp8_f32(G[gg * 8 + 0], G[gg * 8 + 1], lo, false);
      lo = __builtin_amdgcn_cvt_pk_fp8_f32(G[gg * 8 + 2], G[gg * 8 + 3], lo, true);
      hi = __builtin_amdgcn_cvt_pk_fp8_f32(G[gg * 8 + 4], G[gg * 8 + 5], hi, false);
      hi = __builtin_amdgcn_cvt_pk_fp8_f32(G[gg * 8 + 6], G[gg * 8 + 7], hi, true);
      union { int i2[2]; long l; } u; u.i2[0] = lo; u.i2[1] = hi;
      uint32_t addr = ldsB + (uint32_t)kt * 2048u + (uint32_t)gg * 512u
                    + (uint32_t)(lane >> 4) * 128u
                    + (uint32_t)((lane + gg) & 15) * 8u;
      DSWRITE_B64(addr, u.l);
    }
    WAIT_LGKM0;   // write-data hazard guard (asm writes invisible to compiler)
  };

  issueBatch(0, GR);
#pragma unroll
  for (int bt = 0; bt < 8; ++bt) {
    if (bt < 7) {
      if (bt & 1) issueBatch(bt + 1, GR); else issueBatch(bt + 1, GS);
      WAIT_VMCNT(32);
    } else {
      WAIT_VMCNT(0);
    }
    SCHEDBAR();
    if (bt & 1) packWrite(GS, bt); else packWrite(GR, bt);
  }
  sqx[w][lane] = sq;
  __syncthreads();
  if (tid < 64)
    invd[tid] = rsqrtf(fmaxf(sqx[0][tid] + sqx[1][tid], 1e-24f))
              * 1.44269504088896340736f;   // fold log2(e)
  __syncthreads();

  float iv[4], cxj[4];
#pragma unroll
  for (int q = 0; q < 4; ++q) {
    iv[q] = invd[q * 16 + l15];
    cxj[q] = (float)(q * 16 + l15) + 0.5f;   // cx = (j & 63) + 0.5
  }

  // ---- phase 2: 3 chunks x 96 rows, 16 k-steps each ----
  // A-frag for step s (c = s>>4, kt = s&15), mi: rowgroup c*12 + w*6 + mi
  const uint32_t vA0 = (uint32_t)b * APANEL8 + (uint32_t)(w * 6) * 512u
                     + (uint32_t)lane * 8u;
  long afA[6], afB[6];

  auto issueA = [&](int s, long (&af)[6]) {
    int c = s >> 4, kt = s & 15;
    uint32_t base = vA0 + (uint32_t)(c * 12) * 512u + (uint32_t)kt * ATILE8;
#pragma unroll
    for (int mi = 0; mi < 6; ++mi)
      GLOAD_B64(af[mi], base + (uint32_t)mi * 512u, sA);
  };

  issueA(0, afA);
  issueA(1, afB);

#pragma unroll
  for (int c = 0; c < 3; ++c) {
    floatx4 acc[6][4];
#pragma unroll
    for (int mi = 0; mi < 6; ++mi)
#pragma unroll
      for (int q = 0; q < 4; ++q) acc[mi][q] = (floatx4){0.f, 0.f, 0.f, 0.f};

#pragma unroll
    for (int kt = 0; kt < 16; ++kt) {
      const int s = c * 16 + kt;
      if (s == 47) { WAIT_VMCNT(0); } else { WAIT_VMCNT(6); }
      SCHEDBAR();
      // B-frag reads: plain LDS loads (compiler handles lgkmcnt); bank-floor layout
#pragma unroll
      for (int q = 0; q < 4; ++q) {
        long bfr = *(const long*)(Bsh + (uint32_t)kt * 2048u + (uint32_t)g * 512u
                                  + (uint32_t)q * 128u
                                  + (uint32_t)((l15 + g) & 15) * 8u);
        if (kt & 1) {
#pragma unroll
          for (int mi = 0; mi < 6; ++mi)
            acc[mi][q] = __builtin_amdgcn_mfma_f32_16x16x32_fp8_fp8(afB[mi], bfr, acc[mi][q], 0, 0, 0);
        } else {
#pragma unroll
          for (int mi = 0; mi < 6; ++mi)
            acc[mi][q] = __builtin_amdgcn_mfma_f32_16x16x32_fp8_fp8(afA[mi], bfr, acc[mi][q], 0, 0, 0);
        }
      }
      if (s + 2 < 48) {
        if (kt & 1) issueA(s + 2, afB); else issueA(s + 2, afA);
      }
    }

    // ---- epilogue for chunk c (cy = jc + 0.5 handled in finalize) ----
#pragma unroll
    for (int mi = 0; mi < 6; ++mi) {
      float s4[4] = {0.f, 0.f, 0.f, 0.f}, sx4[4] = {0.f, 0.f, 0.f, 0.f};
#pragma unroll
      for (int q = 0; q < 4; ++q)
#pragma unroll
        for (int r = 0; r < 4; ++r) {
          float p = exp2f(acc[mi][q][r] * iv[q]);
          s4[r] += p;
          sx4[r] = fmaf(p, cxj[q], sx4[r]);
        }
#pragma unroll
      for (int r = 0; r < 4; ++r) {
#pragma unroll
        for (int m = 1; m < 16; m <<= 1) {
          s4[r] += __shfl_xor(s4[r], m);
          sx4[r] += __shfl_xor(sx4[r], m);
        }
      }
      if (l15 == 0) {
#pragma unroll
        for (int r = 0; r < 4; ++r) {
          int row = c * 192 + w * 96 + mi * 16 + g * 4 + r;
          float* o = partials + ((size_t)(b * NP + row) * 64 + jc) * 2;
          o[0] = s4[r];
          o[1] = sx4[r];
        }
      }
    }
  }
}

// ---------------- K4: finalize ----------------
__global__ void finalize_kernel(const float* __restrict__ partials, float* __restrict__ out) {
  int b = blockIdx.x;
  int t = threadIdx.x;
  float sxt = 0.f, syt = 0.f;
  for (int i = t; i < NP; i += 256) {
    const float* p = partials + ((size_t)(b * NP + i) * 64) * 2;
    float s = 0.f, sx = 0.f, sy = 0.f;
#pragma unroll
    for (int jc2 = 0; jc2 < 64; ++jc2) {
      float ss = p[jc2 * 2];
      s += ss;
      sx += p[jc2 * 2 + 1];
      sy = fmaf(ss, (float)jc2 + 0.5f, sy);
    }
    sxt += sx / s;
    syt += sy / s;
  }
  __shared__ float rs[256], rs2[256];
  rs[t] = sxt; rs2[t] = syt;
  __syncthreads();
  for (int o = 128; o > 0; o >>= 1) {
    if (t < o) { rs[t] += rs[t + o]; rs2[t] += rs2[t + o]; }
    __syncthreads();
  }
  if (t == 0) {
    float cx = rs[0] / (float)NP, cy = rs2[0] / (float)NP;
    float l = fmaxf(cx - 12.f, 0.f);
    float tp = fmaxf(cy - 12.f, 0.f);
    out[b * 4 + 0] = l;
    out[b * 4 + 1] = tp;
    out[b * 4 + 2] = fminf(l + 24.f, 64.f);
    out[b * 4 + 3] = fminf(tp + 24.f, 64.f);
  }
}

extern "C" void kernel_launch(void* const* d_in, const int* in_sizes, int n_in,
                              void* d_out, int out_size, void* d_ws, size_t ws_size,
                              hipStream_t stream) {
  const float* patch_x = (const float*)d_in[0];
  const float* x = (const float*)d_in[1];
  float* out = (float*)d_out;
  char* ws = (char*)d_ws;

  float* inv_src = (float*)(ws + 0);                  //    73,728 B
  uint8_t* A2 = (uint8_t*)(ws + 73728);               //  9,437,184 B (fp8)
  float* partials = (float*)(ws + 9510912);           //  9,437,184 B

  norms_kernel<<<dim3((NB * NP + 255) / 256), 256, 0, stream>>>(patch_x, inv_src, NP, NB * NP);
  transpose_kernel<<<dim3(NP / 64, NC / 64, NB), 256, 0, stream>>>(patch_x, inv_src, A2, NP);
  affinity_kernel<<<dim3(NB * 64), 128, 0, stream>>>(A2, x, partials);
  finalize_kernel<<<NB, 256, 0, stream>>>(partials, out);
}